// Round 3
// baseline (500.341 us; speedup 1.0000x reference)
//
#include <hip/hip_runtime.h>
#include <hip/hip_fp16.h>
#include <math.h>

typedef _Float16 half_t;
typedef _Float16 h8_t __attribute__((ext_vector_type(8)));
typedef _Float16 h4_t __attribute__((ext_vector_type(4)));
typedef float f4_t __attribute__((ext_vector_type(4)));
typedef unsigned int u32;

#define MFMA16(a, b, c) __builtin_amdgcn_mfma_f32_16x16x32_f16(a, b, c, 0, 0, 0)

static constexpr int kB = 4;
static constexpr int kS = 2048;
static constexpr int kD = 1024;
static constexpr int BM = 128;
static constexpr int BN = 128;
static constexpr int BK = 32;
// LDS tile layout (unpadded, DMA-compatible, conflict-free for b128 frag reads):
// [kb 0..3][row 0..127][8 halves], 4096 halves = 8KB per tile.
static constexpr int TILE_H = 4096;

// async global->LDS DMA, 16B per lane, LDS dest = wave-uniform base + lane*16
__device__ __forceinline__ void gld16(const half_t* g, half_t* l) {
  __builtin_amdgcn_global_load_lds(
      (const __attribute__((address_space(1))) u32*)g,
      (__attribute__((address_space(3))) u32*)l, 16, 0, 0);
}

// ---------- NT GEMM core: C[128,128] += A[128,K] * B[128,K]^T ----------
// Double-buffered, one barrier per K-iter: DMA(k+1) is issued right after the
// barrier and has the whole MFMA phase of iter k to complete; the compiler's
// vmcnt(0)+lgkmcnt(0) drain before s_barrier provides exactly the needed waits.
template <bool SPLIT>
__device__ __forceinline__ void gemm_core(const half_t* __restrict__ Ahi,
                                          const half_t* __restrict__ Alo, int lda,
                                          const half_t* __restrict__ Bhi,
                                          const half_t* __restrict__ Blo, int ldb,
                                          int k_iters, half_t* sm, f4_t acc[4][4]) {
  const int lane = threadIdx.x & 63;
  const int wid = threadIdx.x >> 6;
  const int wm = (wid >> 1) * 64;
  const int wn = (wid & 1) * 64;
  const int fr = lane & 15;
  const int quad = lane >> 4;
  constexpr int NT = SPLIT ? 4 : 2;      // tiles per buffer (Ah,Bh[,Al,Bl])
  constexpr int BUF_H = NT * TILE_H;     // halves per double-buffer half

  // staging: wave `wid` stages k-block kb=wid; rows (lane) and (lane+64).
  const size_t ga0 = (size_t)lane * lda + wid * 8;
  const size_t ga1 = ga0 + (size_t)64 * lda;
  const size_t gb0 = (size_t)lane * ldb + wid * 8;
  const size_t gb1 = gb0 + (size_t)64 * ldb;
  const int lofs0 = wid * 1024;  // cells [wid*128 + 0..63] (lane*16B within)
  const int lofs1 = lofs0 + 512;

  auto stage = [&](int kk, int pb) {
    half_t* base = sm + pb * BUF_H;
    const size_t ko = (size_t)kk * BK;
    gld16(Ahi + ko + ga0, base + lofs0);
    gld16(Ahi + ko + ga1, base + lofs1);
    gld16(Bhi + ko + gb0, base + TILE_H + lofs0);
    gld16(Bhi + ko + gb1, base + TILE_H + lofs1);
    if constexpr (SPLIT) {
      gld16(Alo + ko + ga0, base + 2 * TILE_H + lofs0);
      gld16(Alo + ko + ga1, base + 2 * TILE_H + lofs1);
      gld16(Blo + ko + gb0, base + 3 * TILE_H + lofs0);
      gld16(Blo + ko + gb1, base + 3 * TILE_H + lofs1);
    }
  };

  const int fbase = quad * 1024 + fr * 8;  // frag offset: kb=quad, row=fr(+i*16+wm)

  stage(0, 0);
  for (int kk = 0; kk < k_iters; ++kk) {
    __syncthreads();  // drains vmcnt: DMA(kk) landed; protects buffer reuse
    if (kk + 1 < k_iters) stage(kk + 1, (kk + 1) & 1);
    half_t* base = sm + (kk & 1) * BUF_H;
    h8_t a[4], b[4], al[4], bl[4];
#pragma unroll
    for (int i = 0; i < 4; ++i) {
      a[i] = *(h8_t*)&base[fbase + (wm + i * 16) * 8];
      b[i] = *(h8_t*)&base[TILE_H + fbase + (wn + i * 16) * 8];
      if constexpr (SPLIT) {
        al[i] = *(h8_t*)&base[2 * TILE_H + fbase + (wm + i * 16) * 8];
        bl[i] = *(h8_t*)&base[3 * TILE_H + fbase + (wn + i * 16) * 8];
      }
    }
#pragma unroll
    for (int i = 0; i < 4; ++i)
#pragma unroll
      for (int j = 0; j < 4; ++j) {
        acc[i][j] = MFMA16(a[i], b[j], acc[i][j]);
        if constexpr (SPLIT) {
          acc[i][j] = MFMA16(a[i], bl[j], acc[i][j]);
          acc[i][j] = MFMA16(al[i], b[j], acc[i][j]);
        }
      }
  }
}

// ---------- Q = X * WQK^T (split, fp32-accurate), write Qhi/Qlo fp16 split ----------
__global__ __launch_bounds__(256) void gemm_q_kernel(
    const half_t* __restrict__ Xhi, const half_t* __restrict__ Xlo,
    const half_t* __restrict__ Whi, const half_t* __restrict__ Wlo,
    half_t* __restrict__ Qhi, half_t* __restrict__ Qlo) {
  __shared__ half_t sm[2 * 4 * TILE_H];  // 64KB
  const size_t arow = (size_t)blockIdx.y * BM;
  const size_t brow = (size_t)blockIdx.x * BN;
  f4_t acc[4][4] = {};
  gemm_core<true>(Xhi + arow * kD, Xlo + arow * kD, kD,
                  Whi + brow * kD, Wlo + brow * kD, kD, kD / BK, sm, acc);
  const int lane = threadIdx.x & 63;
  const int wid = threadIdx.x >> 6;
  const int wm = (wid >> 1) * 64, wn = (wid & 1) * 64;
  const int c16 = lane & 15, r4 = (lane >> 4) * 4;
#pragma unroll
  for (int i = 0; i < 4; ++i)
#pragma unroll
    for (int j = 0; j < 4; ++j)
#pragma unroll
      for (int r = 0; r < 4; ++r) {
        const size_t row = arow + wm + i * 16 + r4 + r;
        const size_t col = brow + wn + j * 16 + c16;
        const float q = acc[i][j][r];
        const half_t qh = (half_t)q;
        const half_t ql = (half_t)(q - (float)qh);
        const size_t idx = row * kD + col;
        Qhi[idx] = qh;
        Qlo[idx] = ql;
      }
}

// ---------- V = X * WOV^T (single-pass fp16), stored transposed: Vt[b][e][t] ----------
__global__ __launch_bounds__(256) void gemm_v_kernel(
    const half_t* __restrict__ Xhi, const half_t* __restrict__ Whi,
    half_t* __restrict__ Vt) {
  __shared__ half_t sm[2 * 2 * TILE_H];  // 32KB
  const size_t arow = (size_t)blockIdx.y * BM;
  const size_t brow = (size_t)blockIdx.x * BN;
  f4_t acc[4][4] = {};
  gemm_core<false>(Xhi + arow * kD, nullptr, kD, Whi + brow * kD, nullptr, kD,
                   kD / BK, sm, acc);
  const int lane = threadIdx.x & 63;
  const int wid = threadIdx.x >> 6;
  const int wm = (wid >> 1) * 64, wn = (wid & 1) * 64;
  const int c16 = lane & 15, r4 = (lane >> 4) * 4;
#pragma unroll
  for (int i = 0; i < 4; ++i)
#pragma unroll
    for (int j = 0; j < 4; ++j)
#pragma unroll
      for (int r = 0; r < 4; ++r) {
        const size_t row = arow + wm + i * 16 + r4 + r;  // global 0..8191
        const size_t col = brow + wn + j * 16 + c16;     // e: 0..1023
        const size_t bi = row >> 11;
        const size_t s = row & 2047;
        Vt[bi * (size_t)kD * kS + col * kS + s] = (half_t)acc[i][j][r];
      }
}

// ---------- Sc = 32 * Q * X^T, causal tiles only, raw scores into d_out A region ----------
__global__ __launch_bounds__(256) void gemm_score_kernel(
    const half_t* __restrict__ Qhi, const half_t* __restrict__ Qlo,
    const half_t* __restrict__ Xhi, const half_t* __restrict__ Xlo,
    float* __restrict__ Sc) {
  const int tn = blockIdx.x, tm = blockIdx.y, bi = blockIdx.z;
  if (tn > tm) return;  // fully masked tile: softmax never reads it
  __shared__ half_t sm[2 * 4 * TILE_H];  // 64KB
  const size_t arow = (size_t)bi * kS + (size_t)tm * BM;
  const size_t brow = (size_t)bi * kS + (size_t)tn * BN;
  f4_t acc[4][4] = {};
  gemm_core<true>(Qhi + arow * kD, Qlo + arow * kD, kD,
                  Xhi + brow * kD, Xlo + brow * kD, kD, kD / BK, sm, acc);
  float* out = Sc + (size_t)bi * kS * kS;
  const int lane = threadIdx.x & 63;
  const int wid = threadIdx.x >> 6;
  const int wm = (wid >> 1) * 64, wn = (wid & 1) * 64;
  const int c16 = lane & 15, r4 = (lane >> 4) * 4;
#pragma unroll
  for (int i = 0; i < 4; ++i)
#pragma unroll
    for (int j = 0; j < 4; ++j)
#pragma unroll
      for (int r = 0; r < 4; ++r) {
        const int row = tm * BM + wm + i * 16 + r4 + r;
        const int col = tn * BN + wn + j * 16 + c16;
        out[(size_t)row * kS + col] = 32.0f * acc[i][j][r];
      }
}

// ---------- row softmax (causal), in-place on d_out A region + fp16 copy ----------
__global__ __launch_bounds__(256) void softmax_kernel(float* __restrict__ A,
                                                      half_t* __restrict__ Ah) {
  const int rgl = blockIdx.x;  // 0..8191
  const int s = rgl & 2047;
  float* row = A + (size_t)rgl * kS;
  half_t* hrow = Ah + (size_t)rgl * kS;
  const int tid = threadIdx.x;
  const int n = s + 1;
  float v[8];
  float mx = -INFINITY;
#pragma unroll
  for (int i = 0; i < 8; ++i) {
    const int t = tid + i * 256;
    v[i] = (t < n) ? row[t] : -INFINITY;
    mx = fmaxf(mx, v[i]);
  }
  for (int off = 32; off; off >>= 1) mx = fmaxf(mx, __shfl_xor(mx, off));
  __shared__ float red[8];
  const int lane = tid & 63, wid = tid >> 6;
  if (lane == 0) red[wid] = mx;
  __syncthreads();
  if (tid == 0) {
    float m = fmaxf(fmaxf(red[0], red[1]), fmaxf(red[2], red[3]));
    red[4] = m;
  }
  __syncthreads();
  mx = red[4];
  float sum = 0.0f;
#pragma unroll
  for (int i = 0; i < 8; ++i) {
    v[i] = (tid + i * 256 < n) ? __expf(v[i] - mx) : 0.0f;
    sum += v[i];
  }
  for (int off = 32; off; off >>= 1) sum += __shfl_xor(sum, off);
  __syncthreads();
  if (lane == 0) red[wid] = sum;
  __syncthreads();
  if (tid == 0) red[5] = 1.0f / (red[0] + red[1] + red[2] + red[3]);
  __syncthreads();
  const float inv = red[5];
#pragma unroll
  for (int i = 0; i < 8; ++i) {
    const int t = tid + i * 256;
    const float a = v[i] * inv;  // zero for t > s (v[i]==0 there)
    row[t] = a;
    hrow[t] = (half_t)a;
  }
}

// ---------- Y = A * V (causal K range), epilogue Out0 = X + Y ----------
__global__ __launch_bounds__(256) void gemm_y_kernel(
    const half_t* __restrict__ Ah, const half_t* __restrict__ Vt,
    const float* __restrict__ X, float* __restrict__ Out) {
  __shared__ half_t sm[2 * 2 * TILE_H];  // 32KB
  const int tn = blockIdx.x, tm = blockIdx.y, bi = blockIdx.z;
  const size_t abase = ((size_t)bi * kS + (size_t)tm * BM) * kS;
  const size_t bbase = ((size_t)bi * kD + (size_t)tn * BN) * kS;
  f4_t acc[4][4] = {};
  gemm_core<false>(Ah + abase, nullptr, kS, Vt + bbase, nullptr, kS,
                   (tm + 1) * BM / BK, sm, acc);
  const size_t obase = (size_t)bi * kS * kD;
  const int lane = threadIdx.x & 63;
  const int wid = threadIdx.x >> 6;
  const int wm = (wid >> 1) * 64, wn = (wid & 1) * 64;
  const int c16 = lane & 15, r4 = (lane >> 4) * 4;
#pragma unroll
  for (int i = 0; i < 4; ++i)
#pragma unroll
    for (int j = 0; j < 4; ++j)
#pragma unroll
      for (int r = 0; r < 4; ++r) {
        const size_t row = (size_t)tm * BM + wm + i * 16 + r4 + r;
        const size_t col = (size_t)tn * BN + wn + j * 16 + c16;
        const size_t idx = obase + row * kD + col;
        Out[idx] = X[idx] + acc[i][j][r];
      }
}

// ---------- fp32 -> fp16 hi/lo split (and hi-only convert) ----------
__global__ __launch_bounds__(256) void split_kernel(const float* __restrict__ x,
                                                    half_t* __restrict__ hi,
                                                    half_t* __restrict__ lo, int n4) {
  const int i = blockIdx.x * 256 + threadIdx.x;
  if (i >= n4) return;
  const float4 v = ((const float4*)x)[i];
  const float vv[4] = {v.x, v.y, v.z, v.w};
  h4_t h, l;
#pragma unroll
  for (int j = 0; j < 4; ++j) {
    const half_t hh = (half_t)vv[j];
    h[j] = hh;
    l[j] = (half_t)(vv[j] - (float)hh);
  }
  ((h4_t*)hi)[i] = h;
  ((h4_t*)lo)[i] = l;
}

__global__ __launch_bounds__(256) void cvt_kernel(const float* __restrict__ x,
                                                  half_t* __restrict__ hi, int n4) {
  const int i = blockIdx.x * 256 + threadIdx.x;
  if (i >= n4) return;
  const float4 v = ((const float4*)x)[i];
  h4_t h;
  h[0] = (half_t)v.x; h[1] = (half_t)v.y; h[2] = (half_t)v.z; h[3] = (half_t)v.w;
  ((h4_t*)hi)[i] = h;
}

extern "C" void kernel_launch(void* const* d_in, const int* in_sizes, int n_in,
                              void* d_out, int out_size, void* d_ws, size_t ws_size,
                              hipStream_t stream) {
  const float* X   = (const float*)d_in[0];
  // d_in[1] = causal mask: deterministic (tril), recomputed on the fly — unused
  const float* WQK = (const float*)d_in[2];
  const float* WOV = (const float*)d_in[3];

  constexpr size_t nX = (size_t)kB * kS * kD;   // 8388608
  constexpr size_t nW = (size_t)kD * kD;        // 1048576
  constexpr size_t nA = (size_t)kB * kS * kS;   // 16777216

  float* out0 = (float*)d_out;        // X + Y
  float* outA = out0 + nX;            // A (also used as raw-score scratch)

  // workspace layout (fp16 elements)
  half_t* ws = (half_t*)d_ws;
  half_t* Xhi = ws; ws += nX;
  half_t* Xlo = ws; ws += nX;
  half_t* Qhi = ws; ws += nX;
  half_t* Qlo = ws; ws += nX;
  half_t* Whi = ws; ws += nW;
  half_t* Wlo = ws; ws += nW;
  half_t* WVh = ws; ws += nW;
  half_t* Vt  = ws; ws += nX;
  half_t* Ah  = ws; ws += nA;
  const size_t need_bytes = (size_t)((char*)ws - (char*)d_ws);
  if (ws_size < need_bytes) return;  // workspace too small: fail loudly (stub output)

  split_kernel<<<(int)(nX / 4 / 256), 256, 0, stream>>>(X, Xhi, Xlo, (int)(nX / 4));
  split_kernel<<<(int)(nW / 4 / 256), 256, 0, stream>>>(WQK, Whi, Wlo, (int)(nW / 4));
  cvt_kernel<<<(int)(nW / 4 / 256), 256, 0, stream>>>(WOV, WVh, (int)(nW / 4));

  gemm_q_kernel<<<dim3(kD / BN, kB * kS / BM), 256, 0, stream>>>(Xhi, Xlo, Whi, Wlo, Qhi, Qlo);
  gemm_v_kernel<<<dim3(kD / BN, kB * kS / BM), 256, 0, stream>>>(Xhi, WVh, Vt);
  gemm_score_kernel<<<dim3(kS / BN, kS / BM, kB), 256, 0, stream>>>(Qhi, Qlo, Xhi, Xlo, outA);
  softmax_kernel<<<kB * kS, 256, 0, stream>>>(outA, Ah);
  gemm_y_kernel<<<dim3(kD / BN, kS / BM, kB), 256, 0, stream>>>(Ah, Vt, X, out0);
}

// Round 4
// 476.103 us; speedup vs baseline: 1.0509x; 1.0509x over previous
//
#include <hip/hip_runtime.h>
#include <hip/hip_fp16.h>
#include <math.h>

typedef _Float16 half_t;
typedef _Float16 h8_t __attribute__((ext_vector_type(8)));
typedef _Float16 h4_t __attribute__((ext_vector_type(4)));
typedef float f4_t __attribute__((ext_vector_type(4)));

#define MFMA16(a, b, c) __builtin_amdgcn_mfma_f32_16x16x32_f16(a, b, c, 0, 0, 0)

static constexpr int kB = 4;
static constexpr int kS = 2048;
static constexpr int kD = 1024;
static constexpr int BM = 128;
static constexpr int BN = 128;
static constexpr int BK = 32;
// LDS tile layout [kb 0..3][row 0..127][8 halves] — empirically conflict-free
// (R2/R3 measured SQ_LDS_BANK_CONFLICT == 0 with this read pattern).
static constexpr int TILE_H = 4096;  // halves per 128x32 tile (8 KB)

// ---------- NT GEMM core, 512 threads (8 waves, wave-tile 32x64) ----------
// Single LDS buffer + explicit VGPR pipeline: regs hold tile k+1, loaded right
// after the first barrier so the global loads overlap the MFMA phase of tile k.
template <bool SPLIT>
__device__ __forceinline__ void gemm_core(const half_t* __restrict__ Ahi,
                                          const half_t* __restrict__ Alo, int lda,
                                          const half_t* __restrict__ Bhi,
                                          const half_t* __restrict__ Blo, int ldb,
                                          int k_iters, half_t* sm, f4_t acc[2][4]) {
  half_t* sAh = sm;
  half_t* sBh = sm + TILE_H;
  half_t* sAl = sm + 2 * TILE_H;
  half_t* sBl = sm + 3 * TILE_H;
  const int t = threadIdx.x;
  const int lane = t & 63;
  const int wid = t >> 6;
  const int wm = (wid & 3) * 32;
  const int wn = (wid >> 2) * 64;
  const int fr = lane & 15;
  const int quad = lane >> 4;
  // staging map: quarter-wave-uniform kb, 64B-contiguous per row across quads
  const int srow = wid * 16 + (t & 15);
  const int sq = (t >> 4) & 3;
  const size_t gA = (size_t)srow * lda + sq * 8;
  const size_t gB = (size_t)srow * ldb + sq * 8;
  const int lofs = sq * 1024 + srow * 8;
  const int fbase = quad * 1024 + fr * 8;

  h8_t rA, rB, rAl, rBl;
  rA = *(const h8_t*)&Ahi[gA];
  rB = *(const h8_t*)&Bhi[gB];
  if constexpr (SPLIT) {
    rAl = *(const h8_t*)&Alo[gA];
    rBl = *(const h8_t*)&Blo[gB];
  }

  for (int kk = 0; kk < k_iters; ++kk) {
    *(h8_t*)&sAh[lofs] = rA;
    *(h8_t*)&sBh[lofs] = rB;
    if constexpr (SPLIT) {
      *(h8_t*)&sAl[lofs] = rAl;
      *(h8_t*)&sBl[lofs] = rBl;
    }
    __syncthreads();
    if (kk + 1 < k_iters) {  // prefetch next tile into regs; flies under MFMAs
      const size_t ko = (size_t)(kk + 1) * BK;
      rA = *(const h8_t*)&Ahi[gA + ko];
      rB = *(const h8_t*)&Bhi[gB + ko];
      if constexpr (SPLIT) {
        rAl = *(const h8_t*)&Alo[gA + ko];
        rBl = *(const h8_t*)&Blo[gB + ko];
      }
    }
    h8_t a[2], b[4], al[2], bl[4];
#pragma unroll
    for (int i = 0; i < 2; ++i) {
      a[i] = *(h8_t*)&sAh[fbase + (wm + i * 16) * 8];
      if constexpr (SPLIT) al[i] = *(h8_t*)&sAl[fbase + (wm + i * 16) * 8];
    }
#pragma unroll
    for (int j = 0; j < 4; ++j) {
      b[j] = *(h8_t*)&sBh[fbase + (wn + j * 16) * 8];
      if constexpr (SPLIT) bl[j] = *(h8_t*)&sBl[fbase + (wn + j * 16) * 8];
    }
#pragma unroll
    for (int i = 0; i < 2; ++i)
#pragma unroll
      for (int j = 0; j < 4; ++j) {
        acc[i][j] = MFMA16(a[i], b[j], acc[i][j]);
        if constexpr (SPLIT) {
          acc[i][j] = MFMA16(a[i], bl[j], acc[i][j]);
          acc[i][j] = MFMA16(al[i], b[j], acc[i][j]);
        }
      }
    __syncthreads();
  }
}

// ---------- Q = X * WQK^T (split, fp32-accurate), write Qhi/Qlo fp16 split ----------
__global__ __launch_bounds__(512, 4) void gemm_q_kernel(
    const half_t* __restrict__ Xhi, const half_t* __restrict__ Xlo,
    const half_t* __restrict__ Whi, const half_t* __restrict__ Wlo,
    half_t* __restrict__ Qhi, half_t* __restrict__ Qlo) {
  __shared__ half_t sm[4 * TILE_H];  // 32KB
  const size_t arow = (size_t)blockIdx.y * BM;
  const size_t brow = (size_t)blockIdx.x * BN;
  f4_t acc[2][4] = {};
  gemm_core<true>(Xhi + arow * kD, Xlo + arow * kD, kD,
                  Whi + brow * kD, Wlo + brow * kD, kD, kD / BK, sm, acc);
  const int lane = threadIdx.x & 63;
  const int wid = threadIdx.x >> 6;
  const int wm = (wid & 3) * 32, wn = (wid >> 2) * 64;
  const int c16 = lane & 15, r4 = (lane >> 4) * 4;
#pragma unroll
  for (int i = 0; i < 2; ++i)
#pragma unroll
    for (int j = 0; j < 4; ++j)
#pragma unroll
      for (int r = 0; r < 4; ++r) {
        const size_t row = arow + wm + i * 16 + r4 + r;
        const size_t col = brow + wn + j * 16 + c16;
        const float qv = acc[i][j][r];
        const half_t qh = (half_t)qv;
        const half_t ql = (half_t)(qv - (float)qh);
        const size_t idx = row * kD + col;
        Qhi[idx] = qh;
        Qlo[idx] = ql;
      }
}

// ---------- V = X * WOV^T (single-pass fp16), stored transposed: Vt[b][e][t] ----------
__global__ __launch_bounds__(512, 4) void gemm_v_kernel(
    const half_t* __restrict__ Xhi, const half_t* __restrict__ Whi,
    half_t* __restrict__ Vt) {
  __shared__ half_t sm[2 * TILE_H];  // 16KB
  const size_t arow = (size_t)blockIdx.y * BM;
  const size_t brow = (size_t)blockIdx.x * BN;
  f4_t acc[2][4] = {};
  gemm_core<false>(Xhi + arow * kD, nullptr, kD, Whi + brow * kD, nullptr, kD,
                   kD / BK, sm, acc);
  const int lane = threadIdx.x & 63;
  const int wid = threadIdx.x >> 6;
  const int wm = (wid & 3) * 32, wn = (wid >> 2) * 64;
  const int c16 = lane & 15, r4 = (lane >> 4) * 4;
#pragma unroll
  for (int i = 0; i < 2; ++i)
#pragma unroll
    for (int j = 0; j < 4; ++j)
#pragma unroll
      for (int r = 0; r < 4; ++r) {
        const size_t row = arow + wm + i * 16 + r4 + r;  // global 0..8191
        const size_t col = brow + wn + j * 16 + c16;     // e: 0..1023
        const size_t bi = row >> 11;
        const size_t s = row & 2047;
        Vt[bi * (size_t)kD * kS + col * kS + s] = (half_t)acc[i][j][r];
      }
}

// ---------- Sc = 32 * Q * X^T, causal tiles only, raw scores into d_out A region ----------
__global__ __launch_bounds__(512, 4) void gemm_score_kernel(
    const half_t* __restrict__ Qhi, const half_t* __restrict__ Qlo,
    const half_t* __restrict__ Xhi, const half_t* __restrict__ Xlo,
    float* __restrict__ Sc) {
  const int tn = blockIdx.x, tm = blockIdx.y, bi = blockIdx.z;
  if (tn > tm) return;  // fully masked tile: softmax never reads it
  __shared__ half_t sm[4 * TILE_H];  // 32KB
  const size_t arow = (size_t)bi * kS + (size_t)tm * BM;
  const size_t brow = (size_t)bi * kS + (size_t)tn * BN;
  f4_t acc[2][4] = {};
  gemm_core<true>(Qhi + arow * kD, Qlo + arow * kD, kD,
                  Xhi + brow * kD, Xlo + brow * kD, kD, kD / BK, sm, acc);
  float* out = Sc + (size_t)bi * kS * kS;
  const int lane = threadIdx.x & 63;
  const int wid = threadIdx.x >> 6;
  const int wm = (wid & 3) * 32, wn = (wid >> 2) * 64;
  const int c16 = lane & 15, r4 = (lane >> 4) * 4;
#pragma unroll
  for (int i = 0; i < 2; ++i)
#pragma unroll
    for (int j = 0; j < 4; ++j)
#pragma unroll
      for (int r = 0; r < 4; ++r) {
        const int row = tm * BM + wm + i * 16 + r4 + r;
        const int col = tn * BN + wn + j * 16 + c16;
        out[(size_t)row * kS + col] = 32.0f * acc[i][j][r];
      }
}

// ---------- row softmax (causal), in-place on d_out A region + fp16 copy ----------
__global__ __launch_bounds__(256) void softmax_kernel(float* __restrict__ A,
                                                      half_t* __restrict__ Ah) {
  const int rgl = blockIdx.x;  // 0..8191
  const int s = rgl & 2047;
  float* row = A + (size_t)rgl * kS;
  half_t* hrow = Ah + (size_t)rgl * kS;
  const int tid = threadIdx.x;
  const int n = s + 1;
  float v[8];
  float mx = -INFINITY;
#pragma unroll
  for (int i = 0; i < 8; ++i) {
    const int t = tid + i * 256;
    v[i] = (t < n) ? row[t] : -INFINITY;
    mx = fmaxf(mx, v[i]);
  }
  for (int off = 32; off; off >>= 1) mx = fmaxf(mx, __shfl_xor(mx, off));
  __shared__ float red[8];
  const int lane = tid & 63, wid = tid >> 6;
  if (lane == 0) red[wid] = mx;
  __syncthreads();
  if (tid == 0) {
    float m = fmaxf(fmaxf(red[0], red[1]), fmaxf(red[2], red[3]));
    red[4] = m;
  }
  __syncthreads();
  mx = red[4];
  float sum = 0.0f;
#pragma unroll
  for (int i = 0; i < 8; ++i) {
    v[i] = (tid + i * 256 < n) ? __expf(v[i] - mx) : 0.0f;
    sum += v[i];
  }
  for (int off = 32; off; off >>= 1) sum += __shfl_xor(sum, off);
  __syncthreads();
  if (lane == 0) red[wid] = sum;
  __syncthreads();
  if (tid == 0) red[5] = 1.0f / (red[0] + red[1] + red[2] + red[3]);
  __syncthreads();
  const float inv = red[5];
#pragma unroll
  for (int i = 0; i < 8; ++i) {
    const int t = tid + i * 256;
    const float a = v[i] * inv;  // zero for t > s (v[i]==0 there)
    row[t] = a;
    hrow[t] = (half_t)a;
  }
}

// ---------- Y = A * V (causal K range), epilogue Out0 = X + Y ----------
__global__ __launch_bounds__(512, 4) void gemm_y_kernel(
    const half_t* __restrict__ Ah, const half_t* __restrict__ Vt,
    const float* __restrict__ X, float* __restrict__ Out) {
  __shared__ half_t sm[2 * TILE_H];  // 16KB
  const int tn = blockIdx.x, tm = blockIdx.y, bi = blockIdx.z;
  const size_t abase = ((size_t)bi * kS + (size_t)tm * BM) * kS;
  const size_t bbase = ((size_t)bi * kD + (size_t)tn * BN) * kS;
  f4_t acc[2][4] = {};
  gemm_core<false>(Ah + abase, nullptr, kS, Vt + bbase, nullptr, kS,
                   (tm + 1) * BM / BK, sm, acc);
  const size_t obase = (size_t)bi * kS * kD;
  const int lane = threadIdx.x & 63;
  const int wid = threadIdx.x >> 6;
  const int wm = (wid & 3) * 32, wn = (wid >> 2) * 64;
  const int c16 = lane & 15, r4 = (lane >> 4) * 4;
#pragma unroll
  for (int i = 0; i < 2; ++i)
#pragma unroll
    for (int j = 0; j < 4; ++j)
#pragma unroll
      for (int r = 0; r < 4; ++r) {
        const size_t row = (size_t)tm * BM + wm + i * 16 + r4 + r;
        const size_t col = (size_t)tn * BN + wn + j * 16 + c16;
        const size_t idx = obase + row * kD + col;
        Out[idx] = X[idx] + acc[i][j][r];
      }
}

// ---------- fp32 -> fp16 hi/lo split (and hi-only convert) ----------
__global__ __launch_bounds__(256) void split_kernel(const float* __restrict__ x,
                                                    half_t* __restrict__ hi,
                                                    half_t* __restrict__ lo, int n4) {
  const int i = blockIdx.x * 256 + threadIdx.x;
  if (i >= n4) return;
  const float4 v = ((const float4*)x)[i];
  const float vv[4] = {v.x, v.y, v.z, v.w};
  h4_t h, l;
#pragma unroll
  for (int j = 0; j < 4; ++j) {
    const half_t hh = (half_t)vv[j];
    h[j] = hh;
    l[j] = (half_t)(vv[j] - (float)hh);
  }
  ((h4_t*)hi)[i] = h;
  ((h4_t*)lo)[i] = l;
}

__global__ __launch_bounds__(256) void cvt_kernel(const float* __restrict__ x,
                                                  half_t* __restrict__ hi, int n4) {
  const int i = blockIdx.x * 256 + threadIdx.x;
  if (i >= n4) return;
  const float4 v = ((const float4*)x)[i];
  h4_t h;
  h[0] = (half_t)v.x; h[1] = (half_t)v.y; h[2] = (half_t)v.z; h[3] = (half_t)v.w;
  ((h4_t*)hi)[i] = h;
}

extern "C" void kernel_launch(void* const* d_in, const int* in_sizes, int n_in,
                              void* d_out, int out_size, void* d_ws, size_t ws_size,
                              hipStream_t stream) {
  const float* X   = (const float*)d_in[0];
  // d_in[1] = causal mask: deterministic (tril), recomputed on the fly — unused
  const float* WQK = (const float*)d_in[2];
  const float* WOV = (const float*)d_in[3];

  constexpr size_t nX = (size_t)kB * kS * kD;   // 8388608
  constexpr size_t nW = (size_t)kD * kD;        // 1048576
  constexpr size_t nA = (size_t)kB * kS * kS;   // 16777216

  float* out0 = (float*)d_out;        // X + Y
  float* outA = out0 + nX;            // A (also used as raw-score scratch)

  // workspace layout (fp16 elements)
  half_t* ws = (half_t*)d_ws;
  half_t* Xhi = ws; ws += nX;
  half_t* Xlo = ws; ws += nX;
  half_t* Qhi = ws; ws += nX;
  half_t* Qlo = ws; ws += nX;
  half_t* Whi = ws; ws += nW;
  half_t* Wlo = ws; ws += nW;
  half_t* WVh = ws; ws += nW;
  half_t* Vt  = ws; ws += nX;
  half_t* Ah  = ws; ws += nA;
  const size_t need_bytes = (size_t)((char*)ws - (char*)d_ws);
  if (ws_size < need_bytes) return;  // workspace too small: fail loudly (stub output)

  split_kernel<<<(int)(nX / 4 / 256), 256, 0, stream>>>(X, Xhi, Xlo, (int)(nX / 4));
  split_kernel<<<(int)(nW / 4 / 256), 256, 0, stream>>>(WQK, Whi, Wlo, (int)(nW / 4));
  cvt_kernel<<<(int)(nW / 4 / 256), 256, 0, stream>>>(WOV, WVh, (int)(nW / 4));

  gemm_q_kernel<<<dim3(kD / BN, kB * kS / BM), 512, 0, stream>>>(Xhi, Xlo, Whi, Wlo, Qhi, Qlo);
  gemm_v_kernel<<<dim3(kD / BN, kB * kS / BM), 512, 0, stream>>>(Xhi, WVh, Vt);
  gemm_score_kernel<<<dim3(kS / BN, kS / BM, kB), 512, 0, stream>>>(Qhi, Qlo, Xhi, Xlo, outA);
  softmax_kernel<<<kB * kS, 256, 0, stream>>>(outA, Ah);
  gemm_y_kernel<<<dim3(kD / BN, kS / BM, kB), 512, 0, stream>>>(Ah, Vt, X, out0);
}

// Round 5
// 444.228 us; speedup vs baseline: 1.1263x; 1.0718x over previous
//
#include <hip/hip_runtime.h>
#include <hip/hip_fp16.h>
#include <math.h>

typedef _Float16 half_t;
typedef _Float16 h8_t __attribute__((ext_vector_type(8)));
typedef _Float16 h4_t __attribute__((ext_vector_type(4)));
typedef float f4_t __attribute__((ext_vector_type(4)));

#define MFMA16(a, b, c) __builtin_amdgcn_mfma_f32_16x16x32_f16(a, b, c, 0, 0, 0)

static constexpr int kB = 4;
static constexpr int kS = 2048;
static constexpr int kD = 1024;
static constexpr int BM = 128;
static constexpr int BN = 128;
static constexpr int BK = 32;
// LDS tile layout [kb 0..3][row 0..127][8 halves] — measured 0 bank conflicts (R2-R4).
static constexpr int TILE_H = 4096;  // halves per 128x32 tile (8 KB)

// ---------- NT GEMM core, 256 threads (4 waves, wave-tile 64x64) ----------
// R1-style VGPR staging made explicit: regs prefetch tile k+1 right after the
// barrier so global loads fly under the MFMA phase of tile k.
template <bool SPLIT>
__device__ __forceinline__ void gemm_core(const half_t* __restrict__ Ahi,
                                          const half_t* __restrict__ Alo, int lda,
                                          const half_t* __restrict__ Bhi,
                                          const half_t* __restrict__ Blo, int ldb,
                                          int k_iters, half_t* sm, f4_t acc[4][4]) {
  half_t* sAh = sm;
  half_t* sBh = sm + TILE_H;
  half_t* sAl = sm + 2 * TILE_H;
  half_t* sBl = sm + 3 * TILE_H;
  const int t = threadIdx.x;
  const int lane = t & 63;
  const int wid = t >> 6;
  const int wm = (wid >> 1) * 64;
  const int wn = (wid & 1) * 64;
  const int fr = lane & 15;
  const int quad = lane >> 4;
  // staging map (R4-measured conflict-free): row = wid*16 + (t&15), kb = (t>>4)&3
  const int srow = wid * 16 + (t & 15);
  const int sq = (t >> 4) & 3;
  const size_t gA = (size_t)srow * lda + sq * 8;
  const size_t gB = (size_t)srow * ldb + sq * 8;
  const size_t gA1 = gA + (size_t)64 * lda;
  const size_t gB1 = gB + (size_t)64 * ldb;
  const int l0 = sq * 1024 + srow * 8;
  const int l1 = l0 + 512;  // rows +64
  const int fbase = quad * 1024 + fr * 8;

  h8_t rA0, rA1, rB0, rB1, rAl0, rAl1, rBl0, rBl1;
  rA0 = *(const h8_t*)&Ahi[gA];
  rA1 = *(const h8_t*)&Ahi[gA1];
  rB0 = *(const h8_t*)&Bhi[gB];
  rB1 = *(const h8_t*)&Bhi[gB1];
  if constexpr (SPLIT) {
    rAl0 = *(const h8_t*)&Alo[gA];
    rAl1 = *(const h8_t*)&Alo[gA1];
    rBl0 = *(const h8_t*)&Blo[gB];
    rBl1 = *(const h8_t*)&Blo[gB1];
  }

  for (int kk = 0; kk < k_iters; ++kk) {
    *(h8_t*)&sAh[l0] = rA0;
    *(h8_t*)&sAh[l1] = rA1;
    *(h8_t*)&sBh[l0] = rB0;
    *(h8_t*)&sBh[l1] = rB1;
    if constexpr (SPLIT) {
      *(h8_t*)&sAl[l0] = rAl0;
      *(h8_t*)&sAl[l1] = rAl1;
      *(h8_t*)&sBl[l0] = rBl0;
      *(h8_t*)&sBl[l1] = rBl1;
    }
    __syncthreads();
    if (kk + 1 < k_iters) {  // prefetch next tile; overlaps the MFMA phase
      const size_t ko = (size_t)(kk + 1) * BK;
      rA0 = *(const h8_t*)&Ahi[gA + ko];
      rA1 = *(const h8_t*)&Ahi[gA1 + ko];
      rB0 = *(const h8_t*)&Bhi[gB + ko];
      rB1 = *(const h8_t*)&Bhi[gB1 + ko];
      if constexpr (SPLIT) {
        rAl0 = *(const h8_t*)&Alo[gA + ko];
        rAl1 = *(const h8_t*)&Alo[gA1 + ko];
        rBl0 = *(const h8_t*)&Blo[gB + ko];
        rBl1 = *(const h8_t*)&Blo[gB1 + ko];
      }
    }
    h8_t a[4], b[4], al[4], bl[4];
#pragma unroll
    for (int i = 0; i < 4; ++i) {
      a[i] = *(h8_t*)&sAh[fbase + (wm + i * 16) * 8];
      b[i] = *(h8_t*)&sBh[fbase + (wn + i * 16) * 8];
      if constexpr (SPLIT) {
        al[i] = *(h8_t*)&sAl[fbase + (wm + i * 16) * 8];
        bl[i] = *(h8_t*)&sBl[fbase + (wn + i * 16) * 8];
      }
    }
#pragma unroll
    for (int i = 0; i < 4; ++i)
#pragma unroll
      for (int j = 0; j < 4; ++j) {
        acc[i][j] = MFMA16(a[i], b[j], acc[i][j]);
        if constexpr (SPLIT) {
          acc[i][j] = MFMA16(a[i], bl[j], acc[i][j]);
          acc[i][j] = MFMA16(al[i], b[j], acc[i][j]);
        }
      }
    __syncthreads();
  }
}

// XCD-aware decode for rectangular 64x8 tile grids (q, v):
// XCD = b%8 owns mi = x+8*k; 2x2 supertile snake order within an XCD so
// consecutive same-XCD blocks share operand panels in that XCD's L2.
__device__ __forceinline__ void decode_rect(int b, int& mi, int& ni) {
  const int x = b & 7, s = b >> 3;
  const int st = s >> 2, sub = s & 3;
  const int str = st >> 2;
  int stc = st & 3;
  if (str & 1) stc = 3 - stc;
  const int mil = str * 2 + (sub >> 1);
  ni = stc * 2 + (sub & 1);
  mi = x + 8 * mil;
}

// ---------- Q = X * WQK^T (split, fp32-accurate), write Qhi/Qlo fp16 split ----------
__global__ __launch_bounds__(256) void gemm_q_kernel(
    const half_t* __restrict__ Xhi, const half_t* __restrict__ Xlo,
    const half_t* __restrict__ Whi, const half_t* __restrict__ Wlo,
    half_t* __restrict__ Qhi, half_t* __restrict__ Qlo) {
  __shared__ half_t sm[4 * TILE_H];  // 32KB
  int mi, ni;
  decode_rect(blockIdx.x, mi, ni);
  const size_t arow = (size_t)mi * BM;
  const size_t brow = (size_t)ni * BN;
  f4_t acc[4][4] = {};
  gemm_core<true>(Xhi + arow * kD, Xlo + arow * kD, kD,
                  Whi + brow * kD, Wlo + brow * kD, kD, kD / BK, sm, acc);
  const int lane = threadIdx.x & 63;
  const int wid = threadIdx.x >> 6;
  const int wm = (wid >> 1) * 64, wn = (wid & 1) * 64;
  const int c16 = lane & 15, r4 = (lane >> 4) * 4;
#pragma unroll
  for (int i = 0; i < 4; ++i)
#pragma unroll
    for (int j = 0; j < 4; ++j)
#pragma unroll
      for (int r = 0; r < 4; ++r) {
        const size_t row = arow + wm + i * 16 + r4 + r;
        const size_t col = brow + wn + j * 16 + c16;
        const float qv = acc[i][j][r];
        const half_t qh = (half_t)qv;
        const half_t ql = (half_t)(qv - (float)qh);
        const size_t idx = row * kD + col;
        Qhi[idx] = qh;
        Qlo[idx] = ql;
      }
}

// ---------- V = X * WOV^T (single-pass fp16), stored transposed: Vt[b][e][t] ----------
__global__ __launch_bounds__(256) void gemm_v_kernel(
    const half_t* __restrict__ Xhi, const half_t* __restrict__ Whi,
    half_t* __restrict__ Vt) {
  __shared__ half_t sm[2 * TILE_H];  // 16KB
  int mi, ni;
  decode_rect(blockIdx.x, mi, ni);
  const size_t arow = (size_t)mi * BM;
  const size_t brow = (size_t)ni * BN;
  f4_t acc[4][4] = {};
  gemm_core<false>(Xhi + arow * kD, nullptr, kD, Whi + brow * kD, nullptr, kD,
                   kD / BK, sm, acc);
  const int lane = threadIdx.x & 63;
  const int wid = threadIdx.x >> 6;
  const int wm = (wid >> 1) * 64, wn = (wid & 1) * 64;
  const int c16 = lane & 15, r4 = (lane >> 4) * 4;
#pragma unroll
  for (int i = 0; i < 4; ++i)
#pragma unroll
    for (int j = 0; j < 4; ++j)
#pragma unroll
      for (int r = 0; r < 4; ++r) {
        const size_t row = arow + wm + i * 16 + r4 + r;  // global 0..8191
        const size_t col = brow + wn + j * 16 + c16;     // e: 0..1023
        const size_t bi = row >> 11;
        const size_t s = row & 2047;
        Vt[bi * (size_t)kD * kS + col * kS + s] = (half_t)acc[i][j][r];
      }
}

// ---------- Sc = 32 * Q * X^T, causal tiles only ----------
// XCD x owns row-pair (x, 15-x): 17 tiles/batch, perfectly balanced; tn-
// interleaved order so consecutive same-XCD blocks share the X-panel in L2.
__global__ __launch_bounds__(256) void gemm_score_kernel(
    const half_t* __restrict__ Qhi, const half_t* __restrict__ Qlo,
    const half_t* __restrict__ Xhi, const half_t* __restrict__ Xlo,
    float* __restrict__ Sc) {
  const int x = blockIdx.x & 7;          // XCD / pair id p
  const int s = blockIdx.x >> 3;
  const int bi = s / 17;
  const int ti = s % 17;
  int tm, tn;
  if (ti < 2 * (x + 1)) {
    tn = ti >> 1;
    tm = (ti & 1) ? x : 15 - x;
  } else {
    tn = ti - (x + 1);
    tm = 15 - x;
  }
  __shared__ half_t sm[4 * TILE_H];  // 32KB
  const size_t arow = (size_t)bi * kS + (size_t)tm * BM;
  const size_t brow = (size_t)bi * kS + (size_t)tn * BN;
  f4_t acc[4][4] = {};
  gemm_core<true>(Qhi + arow * kD, Qlo + arow * kD, kD,
                  Xhi + brow * kD, Xlo + brow * kD, kD, kD / BK, sm, acc);
  float* out = Sc + (size_t)bi * kS * kS;
  const int lane = threadIdx.x & 63;
  const int wid = threadIdx.x >> 6;
  const int wm = (wid >> 1) * 64, wn = (wid & 1) * 64;
  const int c16 = lane & 15, r4 = (lane >> 4) * 4;
#pragma unroll
  for (int i = 0; i < 4; ++i)
#pragma unroll
    for (int j = 0; j < 4; ++j)
#pragma unroll
      for (int r = 0; r < 4; ++r) {
        const int row = tm * BM + wm + i * 16 + r4 + r;
        const int col = tn * BN + wn + j * 16 + c16;
        out[(size_t)row * kS + col] = 32.0f * acc[i][j][r];
      }
}

// ---------- row softmax (causal), in-place on d_out A region + fp16 copy ----------
__global__ __launch_bounds__(256) void softmax_kernel(float* __restrict__ A,
                                                      half_t* __restrict__ Ah) {
  const int rgl = blockIdx.x;  // 0..8191
  const int s = rgl & 2047;
  float* row = A + (size_t)rgl * kS;
  half_t* hrow = Ah + (size_t)rgl * kS;
  const int tid = threadIdx.x;
  const int n = s + 1;
  float v[8];
  float mx = -INFINITY;
#pragma unroll
  for (int i = 0; i < 8; ++i) {
    const int t = tid + i * 256;
    v[i] = (t < n) ? row[t] : -INFINITY;
    mx = fmaxf(mx, v[i]);
  }
  for (int off = 32; off; off >>= 1) mx = fmaxf(mx, __shfl_xor(mx, off));
  __shared__ float red[8];
  const int lane = tid & 63, wid = tid >> 6;
  if (lane == 0) red[wid] = mx;
  __syncthreads();
  if (tid == 0) {
    float m = fmaxf(fmaxf(red[0], red[1]), fmaxf(red[2], red[3]));
    red[4] = m;
  }
  __syncthreads();
  mx = red[4];
  float sum = 0.0f;
#pragma unroll
  for (int i = 0; i < 8; ++i) {
    v[i] = (tid + i * 256 < n) ? __expf(v[i] - mx) : 0.0f;
    sum += v[i];
  }
  for (int off = 32; off; off >>= 1) sum += __shfl_xor(sum, off);
  __syncthreads();
  if (lane == 0) red[wid] = sum;
  __syncthreads();
  if (tid == 0) red[5] = 1.0f / (red[0] + red[1] + red[2] + red[3]);
  __syncthreads();
  const float inv = red[5];
#pragma unroll
  for (int i = 0; i < 8; ++i) {
    const int t = tid + i * 256;
    const float a = v[i] * inv;  // zero for t > s (v[i]==0 there)
    row[t] = a;
    hrow[t] = (half_t)a;
  }
}

// ---------- Y = A * V (causal K range), epilogue Out0 = X + Y ----------
// XCD x owns tm-pair (x, 15-x) (equal total K-work = 17 tiles); ni-interleaved
// so consecutive same-XCD blocks share the Vt panel.
__global__ __launch_bounds__(256) void gemm_y_kernel(
    const half_t* __restrict__ Ah, const half_t* __restrict__ Vt,
    const float* __restrict__ X, float* __restrict__ Out) {
  const int x = blockIdx.x & 7;
  const int s = blockIdx.x >> 3;
  const int bi = s >> 4;
  const int ti = s & 15;
  const int tn = ti >> 1;
  const int tm = (ti & 1) ? (15 - x) : x;
  __shared__ half_t sm[2 * TILE_H];  // 16KB
  const size_t abase = ((size_t)bi * kS + (size_t)tm * BM) * kS;
  const size_t bbase = ((size_t)bi * kD + (size_t)tn * BN) * kS;
  f4_t acc[4][4] = {};
  gemm_core<false>(Ah + abase, nullptr, kS, Vt + bbase, nullptr, kS,
                   (tm + 1) * BM / BK, sm, acc);
  const size_t obase = (size_t)bi * kS * kD;
  const int lane = threadIdx.x & 63;
  const int wid = threadIdx.x >> 6;
  const int wm = (wid >> 1) * 64, wn = (wid & 1) * 64;
  const int c16 = lane & 15, r4 = (lane >> 4) * 4;
#pragma unroll
  for (int i = 0; i < 4; ++i)
#pragma unroll
    for (int j = 0; j < 4; ++j)
#pragma unroll
      for (int r = 0; r < 4; ++r) {
        const size_t row = (size_t)tm * BM + wm + i * 16 + r4 + r;
        const size_t col = (size_t)tn * BN + wn + j * 16 + c16;
        const size_t idx = obase + row * kD + col;
        Out[idx] = X[idx] + acc[i][j][r];
      }
}

// ---------- fp32 -> fp16 hi/lo split (and hi-only convert) ----------
__global__ __launch_bounds__(256) void split_kernel(const float* __restrict__ x,
                                                    half_t* __restrict__ hi,
                                                    half_t* __restrict__ lo, int n4) {
  const int i = blockIdx.x * 256 + threadIdx.x;
  if (i >= n4) return;
  const float4 v = ((const float4*)x)[i];
  const float vv[4] = {v.x, v.y, v.z, v.w};
  h4_t h, l;
#pragma unroll
  for (int j = 0; j < 4; ++j) {
    const half_t hh = (half_t)vv[j];
    h[j] = hh;
    l[j] = (half_t)(vv[j] - (float)hh);
  }
  ((h4_t*)hi)[i] = h;
  ((h4_t*)lo)[i] = l;
}

__global__ __launch_bounds__(256) void cvt_kernel(const float* __restrict__ x,
                                                  half_t* __restrict__ hi, int n4) {
  const int i = blockIdx.x * 256 + threadIdx.x;
  if (i >= n4) return;
  const float4 v = ((const float4*)x)[i];
  h4_t h;
  h[0] = (half_t)v.x; h[1] = (half_t)v.y; h[2] = (half_t)v.z; h[3] = (half_t)v.w;
  ((h4_t*)hi)[i] = h;
}

extern "C" void kernel_launch(void* const* d_in, const int* in_sizes, int n_in,
                              void* d_out, int out_size, void* d_ws, size_t ws_size,
                              hipStream_t stream) {
  const float* X   = (const float*)d_in[0];
  // d_in[1] = causal mask: deterministic (tril), recomputed on the fly — unused
  const float* WQK = (const float*)d_in[2];
  const float* WOV = (const float*)d_in[3];

  constexpr size_t nX = (size_t)kB * kS * kD;   // 8388608
  constexpr size_t nW = (size_t)kD * kD;        // 1048576
  constexpr size_t nA = (size_t)kB * kS * kS;   // 16777216

  float* out0 = (float*)d_out;        // X + Y
  float* outA = out0 + nX;            // A (also used as raw-score scratch)

  // workspace layout (fp16 elements)
  half_t* ws = (half_t*)d_ws;
  half_t* Xhi = ws; ws += nX;
  half_t* Xlo = ws; ws += nX;
  half_t* Qhi = ws; ws += nX;
  half_t* Qlo = ws; ws += nX;
  half_t* Whi = ws; ws += nW;
  half_t* Wlo = ws; ws += nW;
  half_t* WVh = ws; ws += nW;
  half_t* Vt  = ws; ws += nX;
  half_t* Ah  = ws; ws += nA;
  const size_t need_bytes = (size_t)((char*)ws - (char*)d_ws);
  if (ws_size < need_bytes) return;  // workspace too small: fail loudly (stub output)

  split_kernel<<<(int)(nX / 4 / 256), 256, 0, stream>>>(X, Xhi, Xlo, (int)(nX / 4));
  split_kernel<<<(int)(nW / 4 / 256), 256, 0, stream>>>(WQK, Whi, Wlo, (int)(nW / 4));
  cvt_kernel<<<(int)(nW / 4 / 256), 256, 0, stream>>>(WOV, WVh, (int)(nW / 4));

  gemm_q_kernel<<<512, 256, 0, stream>>>(Xhi, Xlo, Whi, Wlo, Qhi, Qlo);
  gemm_v_kernel<<<512, 256, 0, stream>>>(Xhi, WVh, Vt);
  gemm_score_kernel<<<544, 256, 0, stream>>>(Qhi, Qlo, Xhi, Xlo, outA);
  softmax_kernel<<<kB * kS, 256, 0, stream>>>(outA, Ah);
  gemm_y_kernel<<<512, 256, 0, stream>>>(Ah, Vt, X, out0);
}